// Round 3
// 470.843 us; speedup vs baseline: 1.0153x; 1.0153x over previous
//
#include <hip/hip_runtime.h>

// EnsembleLayer: y[b, n*32+c] = sum_c' M[n][c][c'] * x[b, clusters[n][c']] + bias[n][c]
// where M[n] = dec_w[n] @ enc_w[n]  (fused encoder+decoder, one pass)
//
// B=131072, F=512, NC=16, CS=32, NH=16.
// This version: double-buffered LDS + software pipeline (prefetch it+1 -> compute it
// -> scatter it+1 -> ONE barrier). Removes the load-latency stall and the
// 2-barrier lockstep that serialized {HBM 65us} + {LDS 68us} + {VALU 42us}.
// (Resubmitted unchanged again: Rounds 1-2 failed with GPUAcquisitionTimeout.)

#define B_ROWS   131072
#define F        512
#define NC       16
#define CS       32
#define NH       16
#define NBLOCKS  1024
#define RPB      128   // rows per block
#define RPI      4     // rows per iteration (keeps prefetch = 8 VGPRs)
#define NITER    (RPB / RPI)

__global__ __launch_bounds__(256, 4)
void ensemble_kernel(const float* __restrict__ x,
                     const int*   __restrict__ clusters,
                     const float* __restrict__ enc_w,
                     const float* __restrict__ enc_b,
                     const float* __restrict__ dec_w,
                     const float* __restrict__ dec_b,
                     float*       __restrict__ out) {
    // xi tile (double-buffered), swizzled within each cluster row: value
    // xi[n*32+c] stored at slot n*32 + ((c + 4n) & 31) -> per-k b128 reads
    // across the 4 cluster-groups of a wave hit 16 distinct banks.
    __shared__ float s_xi[2][RPI][F];   // 16 KB
    __shared__ int   s_tgt[F];          // s_tgt[src_col] = swizzled LDS slot

    const int t = threadIdx.x;

    // ---- build inverse-permutation target table (once per block) ----
    for (int j = t; j < F; j += 256) {
        int col = clusters[j];                 // xi position j sources x column col
        int nn = j >> 5, cc = j & 31;
        s_tgt[col] = (nn << 5) | ((cc + (nn << 2)) & 31);
    }
    __syncthreads();

    // cache my 4 scatter targets (I always load the same 4 source columns)
    const int cbase = (t & 127) << 2;
    const int tgt0 = s_tgt[cbase + 0];
    const int tgt1 = s_tgt[cbase + 1];
    const int tgt2 = s_tgt[cbase + 2];
    const int tgt3 = s_tgt[cbase + 3];

    const int n  = t >> 4;                     // my cluster
    const int c0 = (t & 15) << 1;              // my 2 output columns
    const int rhalf = t >> 7;                  // which row of a 2-row pass I load
    const int row_block = blockIdx.x * RPB;

    // per-thread walking pointers (no 64-bit mul in the loop)
    const float* xp = x + (size_t)(row_block + rhalf) * F + cbase;
    const int xioff = n << 5;
    float* op = out + (size_t)row_block * F + xioff + c0;

    // ---- issue the first tile's loads NOW; latency hides under M-compute ----
    float4 v[2];
    v[0] = *(const float4*)(xp);
    v[1] = *(const float4*)(xp + 2 * F);
    xp += RPI * F;

    // ---- compute my fused M rows + biases (registers) ----
    float m0[32], m1[32];
    #pragma unroll
    for (int i = 0; i < 32; ++i) { m0[i] = 0.f; m1[i] = 0.f; }
    float b0 = dec_b[n * CS + c0];
    float b1 = dec_b[n * CS + c0 + 1];

    for (int h = 0; h < NH; ++h) {
        const float d0 = dec_w[(n * CS + c0)     * NH + h];
        const float d1 = dec_w[(n * CS + c0 + 1) * NH + h];
        const float eb = enc_b[n * NH + h];
        b0 += d0 * eb;
        b1 += d1 * eb;
        const float4* ew = (const float4*)(enc_w + (n * NH + h) * CS);
        #pragma unroll
        for (int k = 0; k < 8; ++k) {
            float4 e = ew[k];
            m0[4*k+0] += d0 * e.x;  m1[4*k+0] += d1 * e.x;
            m0[4*k+1] += d0 * e.y;  m1[4*k+1] += d1 * e.y;
            m0[4*k+2] += d0 * e.z;  m1[4*k+2] += d1 * e.z;
            m0[4*k+3] += d0 * e.w;  m1[4*k+3] += d1 * e.w;
        }
    }

    // ---- scatter tile 0 into buffer 0 ----
    {
        float* d0p = s_xi[0][0 * 2 + rhalf];
        d0p[tgt0] = v[0].x; d0p[tgt1] = v[0].y; d0p[tgt2] = v[0].z; d0p[tgt3] = v[0].w;
        float* d1p = s_xi[0][1 * 2 + rhalf];
        d1p[tgt0] = v[1].x; d1p[tgt1] = v[1].y; d1p[tgt2] = v[1].z; d1p[tgt3] = v[1].w;
    }
    __syncthreads();

    // ---- main pipelined loop: ONE barrier per iteration ----
    for (int it = 0; it < NITER - 1; ++it) {
        const int cur = it & 1;

        // prefetch tile it+1 (consumed only by the scatter below -> the
        // compiler keeps vmcnt open across the whole compute phase)
        v[0] = *(const float4*)(xp);
        v[1] = *(const float4*)(xp + 2 * F);
        xp += RPI * F;

        // compute 4 rows from buffer cur: each thread 2 outputs, 64 FMAs/row
        #pragma unroll
        for (int r = 0; r < RPI; ++r) {
            float a0 = b0, a1 = b1;
            const float* xr = &s_xi[cur][r][xioff];
            #pragma unroll
            for (int k = 0; k < 8; ++k) {
                const int kk = (k + n) & 7;            // swizzled slot for c=4k..4k+3
                float4 xv = *(const float4*)(xr + (kk << 2));
                a0 += m0[4*k+0] * xv.x;  a1 += m1[4*k+0] * xv.x;
                a0 += m0[4*k+1] * xv.y;  a1 += m1[4*k+1] * xv.y;
                a0 += m0[4*k+2] * xv.z;  a1 += m1[4*k+2] * xv.z;
                a0 += m0[4*k+3] * xv.w;  a1 += m1[4*k+3] * xv.w;
            }
            *(float2*)(op + r * F) = make_float2(a0, a1);
        }
        op += RPI * F;

        // scatter prefetched tile into the OTHER buffer (no conflict with
        // this iteration's reads; previous readers of cur^1 finished before
        // the barrier at the end of iteration it-1)
        {
            float* d0p = s_xi[cur ^ 1][0 * 2 + rhalf];
            d0p[tgt0] = v[0].x; d0p[tgt1] = v[0].y; d0p[tgt2] = v[0].z; d0p[tgt3] = v[0].w;
            float* d1p = s_xi[cur ^ 1][1 * 2 + rhalf];
            d1p[tgt0] = v[1].x; d1p[tgt1] = v[1].y; d1p[tgt2] = v[1].z; d1p[tgt3] = v[1].w;
        }
        __syncthreads();
    }

    // ---- peeled final tile: compute only ----
    {
        const int cur = (NITER - 1) & 1;
        #pragma unroll
        for (int r = 0; r < RPI; ++r) {
            float a0 = b0, a1 = b1;
            const float* xr = &s_xi[cur][r][xioff];
            #pragma unroll
            for (int k = 0; k < 8; ++k) {
                const int kk = (k + n) & 7;
                float4 xv = *(const float4*)(xr + (kk << 2));
                a0 += m0[4*k+0] * xv.x;  a1 += m1[4*k+0] * xv.x;
                a0 += m0[4*k+1] * xv.y;  a1 += m1[4*k+1] * xv.y;
                a0 += m0[4*k+2] * xv.z;  a1 += m1[4*k+2] * xv.z;
                a0 += m0[4*k+3] * xv.w;  a1 += m1[4*k+3] * xv.w;
            }
            *(float2*)(op + r * F) = make_float2(a0, a1);
        }
    }
}

extern "C" void kernel_launch(void* const* d_in, const int* in_sizes, int n_in,
                              void* d_out, int out_size, void* d_ws, size_t ws_size,
                              hipStream_t stream) {
    const float* x      = (const float*)d_in[0];
    const int*   clus   = (const int*)  d_in[1];
    const float* enc_w  = (const float*)d_in[2];
    const float* enc_b  = (const float*)d_in[3];
    const float* dec_w  = (const float*)d_in[4];
    const float* dec_b  = (const float*)d_in[5];
    float*       out    = (float*)d_out;

    ensemble_kernel<<<NBLOCKS, 256, 0, stream>>>(x, clus, enc_w, enc_b, dec_w, dec_b, out);
}